// Round 12
// baseline (2737.742 us; speedup 1.0000x reference)
//
#include <hip/hip_runtime.h>
#include <cstddef>

#define B_     512
#define IN_    1023
#define INP1   1024
#define OUT_   512
#define OUT4   128
#define CLIPV  2.0f
#define LNEPS  1e-5f

// fused v3 geometry: 32-row strips, 256-thr blocks, last-arrival finisher
#define S_     32              // strips per sample
#define RS_    32              // rows per strip
#define NBLK   (B_ * S_)       // 16384 blocks
#define KH_    16              // fx4 rows per thread (RS_ / 2 row-groups)

// fallback (R9/R11 proven) geometry
#define G_      4
#define NGRP    128
#define NSLAB   8
#define SLROWS  128
#define K2S     4
#define K2ROWS  256
#define NBS2    (B_ * K2S)

typedef float fx4 __attribute__((ext_vector_type(4)));

__device__ __forceinline__ float2 block_reduce2(float a, float b, float2* lds) {
    #pragma unroll
    for (int off = 32; off; off >>= 1) {
        a += __shfl_down(a, off, 64);
        b += __shfl_down(b, off, 64);
    }
    const int lane = threadIdx.x & 63;
    const int wid  = threadIdx.x >> 6;
    const int nw   = blockDim.x >> 6;
    if (lane == 0) lds[wid] = make_float2(a, b);
    __syncthreads();
    if (wid == 0) {
        float2 v = (lane < nw) ? lds[lane] : make_float2(0.f, 0.f);
        a = v.x; b = v.y;
        #pragma unroll
        for (int off = 8; off; off >>= 1) {
            a += __shfl_down(a, off, 64);
            b += __shfl_down(b, off, 64);
        }
        if (lane == 0) lds[0] = make_float2(a, b);
    }
    __syncthreads();
    float2 r = lds[0];
    __syncthreads();
    return r;
}

// ---------------- fused v3: hebb read ONCE, last-arrival does LN ----------------
__global__ __launch_bounds__(256, 4) void fused_v3(
    const float* __restrict__ x, const float* __restrict__ hebb,
    const float* __restrict__ weight, const float* __restrict__ alpha,
    const float* __restrict__ ln_g, const float* __restrict__ ln_b,
    const float* __restrict__ mod_w, const float* __restrict__ mod_b,
    const float* __restrict__ fan_w, const float* __restrict__ fan_b,
    float* __restrict__ y_out, float* __restrict__ m_out,
    float* __restrict__ hebb_out,
    int* __restrict__ cnt, int* __restrict__ flag)
{
    const int blk = (int)blockIdx.x;      // b*S_ + s  (s fastest -> XCD W/alpha affinity)
    const int b   = blk >> 5;
    const int s   = blk & (S_ - 1);
    const int tid = (int)threadIdx.x;
    const int o4  = tid & 127;
    const int rg  = tid >> 7;             // 0..1 row-groups of 16 rows

    __shared__ float  xs[RS_];
    __shared__ float4 pl[2][OUT4];
    __shared__ float  y_lds[OUT_];
    __shared__ float2 rbuf[16];
    __shared__ int    role;

    const int r0 = s * RS_;
    if (tid < RS_) {
        const int row = r0 + tid;
        xs[tid] = (row < IN_) ? x[(size_t)b * IN_ + row] : 1.0f;   // bias row = 1
    }
    __syncthreads();

    // ---- phase 1: NT-stream strip into registers, partial y_pre ----
    const int rbase = r0 + rg * KH_;
    const fx4*    __restrict__ h4 = (const fx4*)hebb    + ((size_t)b * INP1 + rbase) * OUT4 + o4;
    const float4* __restrict__ w4 = (const float4*)weight + (size_t)rbase * OUT4 + o4;
    const float4* __restrict__ a4 = (const float4*)alpha  + (size_t)rbase * OUT4 + o4;

    fx4 h[KH_];
    float4 acc = make_float4(0.f, 0.f, 0.f, 0.f);
    #pragma unroll
    for (int k = 0; k < KH_; ++k) {
        h[k] = __builtin_nontemporal_load(&h4[(size_t)k * OUT4]);
        const float4 wv = w4[(size_t)k * OUT4];
        const float4 av = a4[(size_t)k * OUT4];
        const float  xv = xs[rg * KH_ + k];
        acc.x = fmaf(xv, fmaf(av.x, h[k].x, wv.x), acc.x);
        acc.y = fmaf(xv, fmaf(av.y, h[k].y, wv.y), acc.y);
        acc.z = fmaf(xv, fmaf(av.z, h[k].z, wv.z), acc.z);
        acc.w = fmaf(xv, fmaf(av.w, h[k].w, wv.w), acc.w);
    }

    pl[rg][o4] = acc;
    __syncthreads();
    if (rg == 0) {
        float4 p = pl[0][o4];
        const float4 q = pl[1][o4];
        p.x += q.x; p.y += q.y; p.z += q.z; p.w += q.w;
        // partial parked in the first 512 floats of this strip's hebb_out region;
        // it is consumed by the finisher BEFORE phase 2 overwrites it.
        ((float4*)hebb_out)[((size_t)b * INP1 + r0) * OUT4 + o4] = p;
    }
    __syncthreads();                      // all waves' stores drained (s_barrier waitcnt)
    if (tid == 0) {
        role = __hip_atomic_fetch_add(&cnt[b], 1, __ATOMIC_ACQ_REL,
                                      __HIP_MEMORY_SCOPE_AGENT);
    }
    __syncthreads();
    const bool finisher = (role == S_ - 1);

    float mval;
    if (finisher) {
        // ---- LN + modulator for sample b (reads the 32 parked partials) ----
        const int oA = tid, oB = tid + 256;
        float yp0 = 0.f, yp1 = 0.f;
        #pragma unroll 4
        for (int ss = 0; ss < S_; ++ss) {
            const float* p = hebb_out + ((size_t)b * INP1 + ss * RS_) * OUT_ / 1
                           ;   // float offset: (b*1024 + ss*32) * 512
            const float* pp = hebb_out + ((size_t)b * INP1 + (size_t)ss * RS_) * OUT_;
            (void)p;
            yp0 += pp[oA];
            yp1 += pp[oB];
        }

        float2 ssm = block_reduce2(yp0 + yp1, yp0 * yp0 + yp1 * yp1, rbuf);
        const float mu   = ssm.x * (1.0f / OUT_);
        const float var  = ssm.y * (1.0f / OUT_) - mu * mu;
        const float rstd = rsqrtf(var + LNEPS);
        const float y0 = tanhf(fmaf(ln_g[oA], (yp0 - mu) * rstd, ln_b[oA]));
        const float y1 = tanhf(fmaf(ln_g[oB], (yp1 - mu) * rstd, ln_b[oB]));
        y_lds[oA] = y0;
        y_lds[oB] = y1;
        y_out[(size_t)b * OUT_ + oA] = y0;
        y_out[(size_t)b * OUT_ + oB] = y1;

        float2 ms = block_reduce2(y0 * mod_w[oA] + y1 * mod_w[oB], 0.f, rbuf);
        mval = tanhf(ms.x + mod_b[0]);
        if (tid == 0) m_out[b] = mval;

        __syncthreads();                  // y/m stores drained to L2
        if (tid == 0)
            __hip_atomic_store(&flag[b], 1, __ATOMIC_RELEASE,
                               __HIP_MEMORY_SCOPE_AGENT);   // wbL2 -> device-visible
    } else {
        // ---- siblings: wait for LN, then pull y/m ----
        if (tid == 0) {
            while (!__hip_atomic_load(&flag[b], __ATOMIC_ACQUIRE,
                                      __HIP_MEMORY_SCOPE_AGENT))
                __builtin_amdgcn_s_sleep(16);
        }
        __syncthreads();                  // acquire (invL2) ordered before these reads
        y_lds[tid]       = y_out[(size_t)b * OUT_ + tid];
        y_lds[tid + 256] = y_out[(size_t)b * OUT_ + tid + 256];
        mval = m_out[b];
        __syncthreads();
    }

    // ---- phase 2: update register-held strip, NT-stream out ----
    const float4 yv4 = ((const float4*)y_lds)[o4];
    const float4 fw  = ((const float4*)fan_w)[o4];
    const float4 fb  = ((const float4*)fan_b)[o4];
    fx4 coef;
    coef.x = fmaf(mval, fw.x, fb.x) * yv4.x;
    coef.y = fmaf(mval, fw.y, fb.y) * yv4.y;
    coef.z = fmaf(mval, fw.z, fb.z) * yv4.z;
    coef.w = fmaf(mval, fw.w, fb.w) * yv4.w;

    fx4* __restrict__ ho4 = (fx4*)hebb_out + ((size_t)b * INP1 + rbase) * OUT4 + o4;
    #pragma unroll
    for (int k = 0; k < KH_; ++k) {
        const float xv = xs[rg * KH_ + k];
        fx4 rr;
        rr.x = fminf(fmaxf(fmaf(coef.x, xv, h[k].x), -CLIPV), CLIPV);
        rr.y = fminf(fmaxf(fmaf(coef.y, xv, h[k].y), -CLIPV), CLIPV);
        rr.z = fminf(fmaxf(fmaf(coef.z, xv, h[k].z), -CLIPV), CLIPV);
        rr.w = fminf(fmaxf(fmaf(coef.w, xv, h[k].w), -CLIPV), CLIPV);
        __builtin_nontemporal_store(rr, &ho4[(size_t)k * OUT4]);
    }
}

// ---------------- fallback path (R9/R11 proven, 591 us) ----------------
__global__ __launch_bounds__(256) void k1a_g4(
    const float* __restrict__ x, const float* __restrict__ hebb,
    const float* __restrict__ weight, const float* __restrict__ alpha,
    float* __restrict__ ws_part)
{
    const int blk  = (int)blockIdx.x;
    const int gid  = blk >> 3;
    const int slab = blk & (NSLAB - 1);
    const int b0   = gid * G_;
    const int tid  = (int)threadIdx.x;
    const int o4   = tid & 127;
    const int half = tid >> 7;

    __shared__ float  xs[G_][SLROWS];
    __shared__ float4 pl[2][OUT4];

    {
        #pragma unroll
        for (int u = 0; u < 2; ++u) {
            const int idx = tid * 2 + u;
            const int g = idx >> 7, j = idx & 127;
            const int row = slab * SLROWS + j;
            xs[g][j] = (row < IN_) ? x[(size_t)(b0 + g) * IN_ + row] : 1.0f;
        }
    }
    __syncthreads();

    const int r0 = slab * SLROWS + half * 64;
    const float4* __restrict__ w4 = (const float4*)weight + (size_t)r0 * OUT4 + o4;
    const float4* __restrict__ a4 = (const float4*)alpha  + (size_t)r0 * OUT4 + o4;

    fx4 acc[G_];
    #pragma unroll
    for (int g = 0; g < G_; ++g) acc[g] = (fx4){0.f, 0.f, 0.f, 0.f};

    #pragma unroll 4
    for (int k = 0; k < 64; ++k) {
        const int j = half * 64 + k;
        const float4 wv = w4[(size_t)k * OUT4];
        const float4 av = a4[(size_t)k * OUT4];
        #pragma unroll
        for (int g = 0; g < G_; ++g) {
            const fx4 h = ((const fx4*)hebb)[((size_t)(b0 + g) * INP1 + r0 + k) * OUT4 + o4];
            const float xv = xs[g][j];
            acc[g].x = fmaf(xv, fmaf(av.x, h.x, wv.x), acc[g].x);
            acc[g].y = fmaf(xv, fmaf(av.y, h.y, wv.y), acc[g].y);
            acc[g].z = fmaf(xv, fmaf(av.z, h.z, wv.z), acc[g].z);
            acc[g].w = fmaf(xv, fmaf(av.w, h.w, wv.w), acc[g].w);
        }
    }

    #pragma unroll
    for (int g = 0; g < G_; ++g) {
        pl[half][o4] = make_float4(acc[g].x, acc[g].y, acc[g].z, acc[g].w);
        __syncthreads();
        if (half == 0) {
            float4 p = pl[0][o4];
            const float4 q = pl[1][o4];
            p.x += q.x; p.y += q.y; p.z += q.z; p.w += q.w;
            ((float4*)ws_part)[((size_t)(b0 + g) * NSLAB + slab) * OUT4 + o4] = p;
        }
        __syncthreads();
    }
}

__global__ __launch_bounds__(256) void k2f_ln_update(
    const float* __restrict__ x, const float* __restrict__ hebb,
    const float* __restrict__ ws_part,
    const float* __restrict__ ln_g, const float* __restrict__ ln_b,
    const float* __restrict__ mod_w, const float* __restrict__ mod_b,
    const float* __restrict__ fan_w, const float* __restrict__ fan_b,
    float* __restrict__ y_out, float* __restrict__ m_out,
    float* __restrict__ hebb_out)
{
    const int bsr = NBS2 - 1 - (int)blockIdx.x;
    const int b   = bsr >> 2;
    const int s   = bsr & 3;
    const int tid = (int)threadIdx.x;

    __shared__ float  xs[K2ROWS];
    __shared__ float  y_lds[OUT_];
    __shared__ float2 rbuf[16];

    const int oA = tid, oB = tid + 256;
    float yp0 = 0.f, yp1 = 0.f;
    #pragma unroll
    for (int s8 = 0; s8 < NSLAB; ++s8) {
        const float* p = ws_part + ((size_t)b * NSLAB + s8) * OUT_;
        yp0 += p[oA];
        yp1 += p[oB];
    }

    float2 ss = block_reduce2(yp0 + yp1, yp0 * yp0 + yp1 * yp1, rbuf);
    const float mu   = ss.x * (1.0f / OUT_);
    const float var  = ss.y * (1.0f / OUT_) - mu * mu;
    const float rstd = rsqrtf(var + LNEPS);
    const float y0 = tanhf(fmaf(ln_g[oA], (yp0 - mu) * rstd, ln_b[oA]));
    const float y1 = tanhf(fmaf(ln_g[oB], (yp1 - mu) * rstd, ln_b[oB]));
    y_lds[oA] = y0;
    y_lds[oB] = y1;

    float2 ms = block_reduce2(y0 * mod_w[oA] + y1 * mod_w[oB], 0.f, rbuf);
    const float mval = tanhf(ms.x + mod_b[0]);
    if (s == 0) {
        y_out[(size_t)b * OUT_ + oA] = y0;
        y_out[(size_t)b * OUT_ + oB] = y1;
        if (tid == 0) m_out[b] = mval;
    }

    {
        const int i = s * K2ROWS + tid;
        xs[tid] = (i < IN_) ? x[(size_t)b * IN_ + i] : 1.0f;
    }
    __syncthreads();

    const int o4   = tid & 127;
    const int half = tid >> 7;
    const float4 yv = ((const float4*)y_lds)[o4];
    const float4 fw = ((const float4*)fan_w)[o4];
    const float4 fb = ((const float4*)fan_b)[o4];
    float4 coef;
    coef.x = fmaf(mval, fw.x, fb.x) * yv.x;
    coef.y = fmaf(mval, fw.y, fb.y) * yv.y;
    coef.z = fmaf(mval, fw.z, fb.z) * yv.z;
    coef.w = fmaf(mval, fw.w, fb.w) * yv.w;

    const int i0 = s * K2ROWS + half * 128;
    const size_t base = ((size_t)b * INP1 + i0) * OUT4 + o4;
    const fx4* __restrict__ h4  = (const fx4*)hebb + base;
    fx4* __restrict__       ho4 = (fx4*)hebb_out + base;
    const float* __restrict__ xk = xs + half * 128;

    #pragma unroll 4
    for (int k = 0; k < 128; ++k) {
        const float xv = xk[k];
        const fx4   h  = h4[(size_t)k * OUT4];
        fx4 r;
        r.x = fminf(fmaxf(fmaf(coef.x, xv, h.x), -CLIPV), CLIPV);
        r.y = fminf(fmaxf(fmaf(coef.y, xv, h.y), -CLIPV), CLIPV);
        r.z = fminf(fmaxf(fmaf(coef.z, xv, h.z), -CLIPV), CLIPV);
        r.w = fminf(fmaxf(fmaf(coef.w, xv, h.w), -CLIPV), CLIPV);
        __builtin_nontemporal_store(r, &ho4[(size_t)k * OUT4]);
    }
}

extern "C" void kernel_launch(void* const* d_in, const int* in_sizes, int n_in,
                              void* d_out, int out_size, void* d_ws, size_t ws_size,
                              hipStream_t stream) {
    const float* x      = (const float*)d_in[0];
    const float* hebb   = (const float*)d_in[1];
    const float* weight = (const float*)d_in[2];
    const float* alpha  = (const float*)d_in[3];
    const float* ln_g   = (const float*)d_in[4];
    const float* ln_b   = (const float*)d_in[5];
    const float* mod_w  = (const float*)d_in[6];
    const float* mod_b  = (const float*)d_in[7];
    const float* fan_w  = (const float*)d_in[8];
    const float* fan_b  = (const float*)d_in[9];

    float* out      = (float*)d_out;
    float* y_out    = out;                               // [B, OUT]
    float* m_out    = out + (size_t)B_ * OUT_;           // [B]
    float* hebb_out = m_out + B_;                        // [B, IN+1, OUT]

    const size_t sync_bytes = 2 * B_ * sizeof(int);      // cnt + flag = 4 KB

    if (ws_size >= sync_bytes) {
        int* cnt  = (int*)d_ws;
        int* flag = cnt + B_;
        hipMemsetAsync(cnt, 0, sync_bytes, stream);
        fused_v3<<<NBLK, 256, 0, stream>>>(
            x, hebb, weight, alpha, ln_g, ln_b, mod_w, mod_b, fan_w, fan_b,
            y_out, m_out, hebb_out, cnt, flag);
    } else {
        float* ws_part = hebb_out;   // consumed before k2 overwrites (R3 pattern)
        k1a_g4<<<NGRP * NSLAB, 256, 0, stream>>>(x, hebb, weight, alpha, ws_part);
        k2f_ln_update<<<NBS2, 256, 0, stream>>>(x, hebb, ws_part,
                                                ln_g, ln_b, mod_w, mod_b,
                                                fan_w, fan_b,
                                                y_out, m_out, hebb_out);
    }
}

// Round 13
// 591.724 us; speedup vs baseline: 4.6267x; 4.6267x over previous
//
#include <hip/hip_runtime.h>
#include <cstddef>

#define B_     512
#define IN_    1023
#define INP1   1024
#define OUT_   512
#define OUT4   128
#define CLIPV  2.0f
#define LNEPS  1e-5f

// k1a grouped geometry (R9 proven): 4 samples/block, 128-row slabs
#define G_      4
#define NGRP    128          // B_/G_
#define NSLAB   8            // INP1/128
#define SLROWS  128

// k2 geometry
#define K2S     4
#define K2ROWS  256
#define NBS2    (B_ * K2S)

typedef float fx4 __attribute__((ext_vector_type(4)));

__device__ __forceinline__ float2 block_reduce2(float a, float b, float2* lds) {
    #pragma unroll
    for (int off = 32; off; off >>= 1) {
        a += __shfl_down(a, off, 64);
        b += __shfl_down(b, off, 64);
    }
    const int lane = threadIdx.x & 63;
    const int wid  = threadIdx.x >> 6;
    const int nw   = blockDim.x >> 6;
    if (lane == 0) lds[wid] = make_float2(a, b);
    __syncthreads();
    if (wid == 0) {
        float2 v = (lane < nw) ? lds[lane] : make_float2(0.f, 0.f);
        a = v.x; b = v.y;
        #pragma unroll
        for (int off = 8; off; off >>= 1) {
            a += __shfl_down(a, off, 64);
            b += __shfl_down(b, off, 64);
        }
        if (lane == 0) lds[0] = make_float2(a, b);
    }
    __syncthreads();
    float2 r = lds[0];
    __syncthreads();
    return r;
}

// k1a: block = (4-sample group, 128-row slab). W/alpha loaded once, reused
// across 4 samples; slab==XCD affinity keeps each XCD's 0.5 MiB W/alpha slab
// L2-resident. 1024 blocks x 256 thr. (R9 proven, byte-identical.)
__global__ __launch_bounds__(256) void k1a_g4(
    const float* __restrict__ x, const float* __restrict__ hebb,
    const float* __restrict__ weight, const float* __restrict__ alpha,
    float* __restrict__ ws_part)
{
    const int blk  = (int)blockIdx.x;      // gid*NSLAB + slab (slab fastest)
    const int gid  = blk >> 3;
    const int slab = blk & (NSLAB - 1);
    const int b0   = gid * G_;
    const int tid  = (int)threadIdx.x;
    const int o4   = tid & 127;
    const int half = tid >> 7;             // 0..1

    __shared__ float  xs[G_][SLROWS];
    __shared__ float4 pl[2][OUT4];

    {   // stage x for the 4 samples' 128 rows (512 values, 2 per thread)
        #pragma unroll
        for (int u = 0; u < 2; ++u) {
            const int idx = tid * 2 + u;
            const int g = idx >> 7, j = idx & 127;
            const int row = slab * SLROWS + j;
            xs[g][j] = (row < IN_) ? x[(size_t)(b0 + g) * IN_ + row] : 1.0f;
        }
    }
    __syncthreads();

    const int r0 = slab * SLROWS + half * 64;
    const float4* __restrict__ w4 = (const float4*)weight + (size_t)r0 * OUT4 + o4;
    const float4* __restrict__ a4 = (const float4*)alpha  + (size_t)r0 * OUT4 + o4;

    fx4 acc[G_];
    #pragma unroll
    for (int g = 0; g < G_; ++g) acc[g] = (fx4){0.f, 0.f, 0.f, 0.f};

    #pragma unroll 4
    for (int k = 0; k < 64; ++k) {
        const int j = half * 64 + k;
        const float4 wv = w4[(size_t)k * OUT4];
        const float4 av = a4[(size_t)k * OUT4];
        #pragma unroll
        for (int g = 0; g < G_; ++g) {
            const fx4 h = ((const fx4*)hebb)[((size_t)(b0 + g) * INP1 + r0 + k) * OUT4 + o4];
            const float xv = xs[g][j];
            acc[g].x = fmaf(xv, fmaf(av.x, h.x, wv.x), acc[g].x);
            acc[g].y = fmaf(xv, fmaf(av.y, h.y, wv.y), acc[g].y);
            acc[g].z = fmaf(xv, fmaf(av.z, h.z, wv.z), acc[g].z);
            acc[g].w = fmaf(xv, fmaf(av.w, h.w, wv.w), acc[g].w);
        }
    }

    #pragma unroll
    for (int g = 0; g < G_; ++g) {
        pl[half][o4] = make_float4(acc[g].x, acc[g].y, acc[g].z, acc[g].w);
        __syncthreads();
        if (half == 0) {
            float4 p = pl[0][o4];
            const float4 q = pl[1][o4];
            p.x += q.x; p.y += q.y; p.z += q.z; p.w += q.w;
            ((float4*)ws_part)[((size_t)(b0 + g) * NSLAB + slab) * OUT4 + o4] = p;
        }
        __syncthreads();
    }
}

// k2f: per (sample, 256-row strip) block: redundant LN+modulator from the 8
// slab partials (L2-hot, 16 KB), then hebb update. 2048 blocks x 256 thr,
// reverse order (L3 tail reuse from k1a). (R11 proven, byte-identical.)
__global__ __launch_bounds__(256) void k2f_ln_update(
    const float* __restrict__ x, const float* __restrict__ hebb,
    const float* __restrict__ ws_part,
    const float* __restrict__ ln_g, const float* __restrict__ ln_b,
    const float* __restrict__ mod_w, const float* __restrict__ mod_b,
    const float* __restrict__ fan_w, const float* __restrict__ fan_b,
    float* __restrict__ y_out, float* __restrict__ m_out,
    float* __restrict__ hebb_out)
{
    const int bsr = NBS2 - 1 - (int)blockIdx.x;   // reverse order
    const int b   = bsr >> 2;
    const int s   = bsr & 3;
    const int tid = (int)threadIdx.x;

    __shared__ float  xs[K2ROWS];
    __shared__ float  y_lds[OUT_];
    __shared__ float2 rbuf[16];

    // ---- LN + modulator (redundant per strip-block) ----
    const int oA = tid, oB = tid + 256;
    float yp0 = 0.f, yp1 = 0.f;
    #pragma unroll
    for (int s8 = 0; s8 < NSLAB; ++s8) {
        const float* p = ws_part + ((size_t)b * NSLAB + s8) * OUT_;
        yp0 += p[oA];
        yp1 += p[oB];
    }

    float2 ss = block_reduce2(yp0 + yp1, yp0 * yp0 + yp1 * yp1, rbuf);
    const float mu   = ss.x * (1.0f / OUT_);
    const float var  = ss.y * (1.0f / OUT_) - mu * mu;
    const float rstd = rsqrtf(var + LNEPS);
    const float y0 = tanhf(fmaf(ln_g[oA], (yp0 - mu) * rstd, ln_b[oA]));
    const float y1 = tanhf(fmaf(ln_g[oB], (yp1 - mu) * rstd, ln_b[oB]));
    y_lds[oA] = y0;
    y_lds[oB] = y1;

    float2 ms = block_reduce2(y0 * mod_w[oA] + y1 * mod_w[oB], 0.f, rbuf);
    const float mval = tanhf(ms.x + mod_b[0]);
    if (s == 0) {
        y_out[(size_t)b * OUT_ + oA] = y0;
        y_out[(size_t)b * OUT_ + oB] = y1;
        if (tid == 0) m_out[b] = mval;
    }

    {   // stage x strip
        const int i = s * K2ROWS + tid;
        xs[tid] = (i < IN_) ? x[(size_t)b * IN_ + i] : 1.0f;
    }
    __syncthreads();   // y_lds + xs visible

    // ---- hebb update ----
    const int o4   = tid & 127;
    const int half = tid >> 7;
    const float4 yv = ((const float4*)y_lds)[o4];
    const float4 fw = ((const float4*)fan_w)[o4];
    const float4 fb = ((const float4*)fan_b)[o4];
    float4 coef;
    coef.x = fmaf(mval, fw.x, fb.x) * yv.x;
    coef.y = fmaf(mval, fw.y, fb.y) * yv.y;
    coef.z = fmaf(mval, fw.z, fb.z) * yv.z;
    coef.w = fmaf(mval, fw.w, fb.w) * yv.w;

    const int i0 = s * K2ROWS + half * 128;
    const size_t base = ((size_t)b * INP1 + i0) * OUT4 + o4;
    const fx4* __restrict__ h4  = (const fx4*)hebb + base;
    fx4* __restrict__       ho4 = (fx4*)hebb_out + base;
    const float* __restrict__ xk = xs + half * 128;

    #pragma unroll 4
    for (int k = 0; k < 128; ++k) {
        const float xv = xk[k];
        const fx4   h  = h4[(size_t)k * OUT4];
        fx4 r;
        r.x = fminf(fmaxf(fmaf(coef.x, xv, h.x), -CLIPV), CLIPV);
        r.y = fminf(fmaxf(fmaf(coef.y, xv, h.y), -CLIPV), CLIPV);
        r.z = fminf(fmaxf(fmaf(coef.z, xv, h.z), -CLIPV), CLIPV);
        r.w = fminf(fmaxf(fmaf(coef.w, xv, h.w), -CLIPV), CLIPV);
        __builtin_nontemporal_store(r, &ho4[(size_t)k * OUT4]);
    }
}

// k1b fallback (only used if ws_part must alias hebb_out)
__global__ __launch_bounds__(512) void k1b_ln_mod(
    const float* __restrict__ ws_part,
    const float* __restrict__ ln_g, const float* __restrict__ ln_b,
    const float* __restrict__ mod_w, const float* __restrict__ mod_b,
    float* __restrict__ y_out, float* __restrict__ m_out)
{
    const int b = (int)blockIdx.x;
    const int o = (int)threadIdx.x;
    __shared__ float2 rbuf[16];

    float ypre = 0.f;
    #pragma unroll
    for (int s = 0; s < NSLAB; ++s)
        ypre += ws_part[((size_t)b * NSLAB + s) * OUT_ + o];

    float2 ss = block_reduce2(ypre, ypre * ypre, rbuf);
    const float mu   = ss.x * (1.0f / OUT_);
    const float var  = ss.y * (1.0f / OUT_) - mu * mu;
    const float rstd = rsqrtf(var + LNEPS);

    const float yv = tanhf(fmaf(ln_g[o], (ypre - mu) * rstd, ln_b[o]));
    y_out[(size_t)b * OUT_ + o] = yv;

    float2 ms = block_reduce2(yv * mod_w[o], 0.f, rbuf);
    if (o == 0) m_out[b] = tanhf(ms.x + mod_b[0]);
}

__global__ __launch_bounds__(256) void k2_update(
    const float* __restrict__ x, const float* __restrict__ hebb,
    const float* __restrict__ y, const float* __restrict__ m,
    const float* __restrict__ fan_w, const float* __restrict__ fan_b,
    float* __restrict__ hebb_out)
{
    const int bsr  = NBS2 - 1 - (int)blockIdx.x;
    const int b    = bsr >> 2;
    const int s    = bsr & 3;
    const int tid  = (int)threadIdx.x;
    const int o4   = tid & 127;
    const int half = tid >> 7;

    __shared__ float xs[K2ROWS];
    {
        const int i = s * K2ROWS + tid;
        xs[tid] = (i < IN_) ? x[(size_t)b * IN_ + i] : 1.0f;
    }
    __syncthreads();

    const float  mb = m[b];
    const float4 yv = ((const float4*)y)[(size_t)b * OUT4 + o4];
    const float4 fw = ((const float4*)fan_w)[o4];
    const float4 fb = ((const float4*)fan_b)[o4];
    float4 coef;
    coef.x = fmaf(mb, fw.x, fb.x) * yv.x;
    coef.y = fmaf(mb, fw.y, fb.y) * yv.y;
    coef.z = fmaf(mb, fw.z, fb.z) * yv.z;
    coef.w = fmaf(mb, fw.w, fb.w) * yv.w;

    const int i0 = s * K2ROWS + half * 128;
    const size_t base = ((size_t)b * INP1 + i0) * OUT4 + o4;
    const fx4* __restrict__ h4  = (const fx4*)hebb + base;
    fx4* __restrict__       ho4 = (fx4*)hebb_out + base;
    const float* __restrict__ xk = xs + half * 128;

    #pragma unroll 4
    for (int k = 0; k < 128; ++k) {
        const float xv = xk[k];
        const fx4   h  = h4[(size_t)k * OUT4];
        fx4 r;
        r.x = fminf(fmaxf(fmaf(coef.x, xv, h.x), -CLIPV), CLIPV);
        r.y = fminf(fmaxf(fmaf(coef.y, xv, h.y), -CLIPV), CLIPV);
        r.z = fminf(fmaxf(fmaf(coef.z, xv, h.z), -CLIPV), CLIPV);
        r.w = fminf(fmaxf(fmaf(coef.w, xv, h.w), -CLIPV), CLIPV);
        __builtin_nontemporal_store(r, &ho4[(size_t)k * OUT4]);
    }
}

extern "C" void kernel_launch(void* const* d_in, const int* in_sizes, int n_in,
                              void* d_out, int out_size, void* d_ws, size_t ws_size,
                              hipStream_t stream) {
    const float* x      = (const float*)d_in[0];
    const float* hebb   = (const float*)d_in[1];
    const float* weight = (const float*)d_in[2];
    const float* alpha  = (const float*)d_in[3];
    const float* ln_g   = (const float*)d_in[4];
    const float* ln_b   = (const float*)d_in[5];
    const float* mod_w  = (const float*)d_in[6];
    const float* mod_b  = (const float*)d_in[7];
    const float* fan_w  = (const float*)d_in[8];
    const float* fan_b  = (const float*)d_in[9];

    float* out      = (float*)d_out;
    float* y_out    = out;                               // [B, OUT]
    float* m_out    = out + (size_t)B_ * OUT_;           // [B]
    float* hebb_out = m_out + B_;                        // [B, IN+1, OUT]

    // partials: B * NSLAB * OUT floats = 8 MiB (ws proven >= 16 MiB in R5/R7)
    const size_t part_bytes = (size_t)B_ * NSLAB * OUT_ * sizeof(float);

    if (ws_size >= part_bytes) {
        float* ws_part = (float*)d_ws;
        k1a_g4<<<NGRP * NSLAB, 256, 0, stream>>>(x, hebb, weight, alpha, ws_part);
        k2f_ln_update<<<NBS2, 256, 0, stream>>>(x, hebb, ws_part,
                                                ln_g, ln_b, mod_w, mod_b,
                                                fan_w, fan_b,
                                                y_out, m_out, hebb_out);
    } else {
        // fallback: ws aliases hebb_out -> partials consumed by k1b before k2
        float* ws_part = hebb_out;
        k1a_g4<<<NGRP * NSLAB, 256, 0, stream>>>(x, hebb, weight, alpha, ws_part);
        k1b_ln_mod<<<B_, OUT_, 0, stream>>>(ws_part, ln_g, ln_b, mod_w, mod_b,
                                            y_out, m_out);
        k2_update<<<NBS2, 256, 0, stream>>>(x, hebb, y_out, m_out,
                                            fan_w, fan_b, hebb_out);
    }
}